// Round 2
// baseline (2719.518 us; speedup 1.0000x reference)
//
#include <hip/hip_runtime.h>
#include <hip/hip_bf16.h>

#define N_ 307
#define B_ 64
#define T_ 12
#define H_ 64
#define E_ 10
#define CH_ 14
#define HM_ 16
#define I2_ 66   // 2*DIN + H
#define GO_ 128  // 2*H
#define UO_ 64
#define QG_ (2 * I2_ * GO_)  // 16896
#define QU_ (2 * I2_ * UO_)  // 8448

__device__ __forceinline__ float wsum(float v) {
    #pragma unroll
    for (int off = 32; off; off >>= 1) v += __shfl_xor(v, off);
    return v;
}
__device__ __forceinline__ float wmax(float v) {
    #pragma unroll
    for (int off = 32; off; off >>= 1) v = fmaxf(v, __shfl_xor(v, off));
    return v;
}
__device__ __forceinline__ float sigm(float x) { return 1.f / (1.f + __expf(-x)); }
__device__ __forceinline__ float ftanh(float x) { return 1.f - 2.f / (__expf(2.f * x) + 1.f); }

// ---------------- P0: supports matrix A = 0.5*(adj_n + softmax(relu(E E^T))) ----------------
__global__ void A_kernel(const float* __restrict__ adj, const float* __restrict__ nemb,
                         float* __restrict__ A) {
    const int n = blockIdx.x;
    const int lane = threadIdx.x; // 64
    float en[E_];
    #pragma unroll
    for (int d = 0; d < E_; ++d) en[d] = nemb[n * E_ + d];
    float asum = 0.f;
    for (int m = lane; m < N_; m += 64) asum += adj[n * N_ + m];
    asum = fmaxf(wsum(asum), 1e-6f);
    float g[5]; bool valid[5];
    float mx = -1e30f;
    #pragma unroll
    for (int it = 0; it < 5; ++it) {
        int m = lane + it * 64;
        valid[it] = (m < N_);
        float dt = 0.f;
        if (valid[it]) {
            #pragma unroll
            for (int e = 0; e < E_; ++e) dt += en[e] * nemb[m * E_ + e];
            dt = fmaxf(dt, 0.f);
            mx = fmaxf(mx, dt);
        }
        g[it] = dt;
    }
    mx = wmax(mx);
    float se = 0.f;
    #pragma unroll
    for (int it = 0; it < 5; ++it)
        if (valid[it]) { g[it] = __expf(g[it] - mx); se += g[it]; }
    se = wsum(se);
    float inv = 1.f / se;
    #pragma unroll
    for (int it = 0; it < 5; ++it) {
        int m = lane + it * 64;
        if (valid[it]) A[n * N_ + m] = 0.5f * (adj[n * N_ + m] / asum + g[it] * inv);
    }
}

// ---------------- P1 fused: all per-node generated weights + W12, one launch ----------------
__device__ __forceinline__ float embdot(const float* __restrict__ nemb, int n,
                                        const float* __restrict__ pool, int Q, int q) {
    float a = 0.f;
    #pragma unroll
    for (int d = 0; d < E_; ++d) a += nemb[n * E_ + d] * pool[d * Q + q];
    return a;
}

__global__ __launch_bounds__(256) void gen_kernel(
    const float* __restrict__ nemb,
    const float* __restrict__ gWp, const float* __restrict__ gbp,
    const float* __restrict__ uWp, const float* __restrict__ ubp,
    const float* __restrict__ mwp,
    const float* __restrict__ W1, const float* __restrict__ W2,
    float* __restrict__ gW, float* __restrict__ gb,
    float* __restrict__ uW, float* __restrict__ ub,
    float* __restrict__ wh, float* __restrict__ W12) {
    const int e0 = N_ * QG_;          // gate_W
    const int e1 = e0 + N_ * GO_;     // gate_b
    const int e2 = e1 + N_ * QU_;     // upd_W
    const int e3 = e2 + N_ * UO_;     // upd_b
    const int e4 = e3 + N_ * H_;      // wh
    const int e5 = e4 + H_ * E_;      // W12
    int idx = blockIdx.x * 256 + threadIdx.x;
    if (idx < e0) {
        int n = idx / QG_, q = idx % QG_;
        gW[idx] = embdot(nemb, n, gWp, QG_, q);
    } else if (idx < e1) {
        int i = idx - e0; int n = i / GO_, q = i % GO_;
        gb[i] = embdot(nemb, n, gbp, GO_, q);
    } else if (idx < e2) {
        int i = idx - e1; int n = i / QU_, q = i % QU_;
        uW[i] = embdot(nemb, n, uWp, QU_, q);
    } else if (idx < e3) {
        int i = idx - e2; int n = i / UO_, q = i % UO_;
        ub[i] = embdot(nemb, n, ubp, UO_, q);
    } else if (idx < e4) {
        int i = idx - e3; int n = i / H_, q = i % H_;
        wh[i] = embdot(nemb, n, mwp, H_, q);
    } else if (idx < e5) {
        int i = idx - e4; int j = i / E_, e = i % E_;
        float a = 0.f;
        #pragma unroll
        for (int q = 0; q < HM_; ++q) a += W1[j * HM_ + q] * W2[q * E_ + e];
        W12[i] = a;
    }
}

// ---------------- P2: hypernet fused: x[t,b,n,2] and emb[t,b,n,10] (h never stored) ----------------
__global__ __launch_bounds__(256) void hyper_kernel(
    const float* __restrict__ hs, const float* __restrict__ src,
    const float* __restrict__ hyper_W, const float* __restrict__ hyper_b,
    const float* __restrict__ wh, const float* __restrict__ W12,
    float* __restrict__ x, float* __restrict__ emb) {
    const int wid = blockIdx.x * 4 + (threadIdx.x >> 6);
    const int lane = threadIdx.x & 63;
    const int t = wid / (B_ * N_);
    const int rem = wid % (B_ * N_);
    const int b = rem / N_;
    const int n = rem % N_;
    float acc = hyper_b[lane];
    #pragma unroll
    for (int c = 0; c < CH_; ++c)
        acc += hs[((b * CH_ + c) * T_ + t) * N_ + n] * hyper_W[c * H_ + lane];
    float h = ftanh(acc);
    float x0 = wsum(h * wh[n * H_ + lane]);
    float my_e = 0.f;
    #pragma unroll
    for (int e = 0; e < E_; ++e) {
        float ve = wsum(h * W12[lane * E_ + e]);
        if (lane == e) my_e = ve;
    }
    if (lane < E_) emb[wid * E_ + lane] = my_e;
    if (lane == 0) {
        x[wid * 2] = x0;
        x[wid * 2 + 1] = src[(b * T_ + t) * N_ + n];
    }
}

// ---------------- P3: all-step diag mask + masked aggregation of the 2 x-channels ----------------
__global__ __launch_bounds__(256) void maskx_kernel(
    const float* __restrict__ A, const float* __restrict__ emb,
    const float* __restrict__ nemb, const float* __restrict__ x,
    float* __restrict__ dmask, float* __restrict__ aggx) {
    const int wid = blockIdx.x * 4 + (threadIdx.x >> 6);
    const int lane = threadIdx.x & 63;
    const int rem = wid % (B_ * N_);
    const int n = rem % N_;
    float et[E_];
    #pragma unroll
    for (int d = 0; d < E_; ++d) et[d] = emb[wid * E_ + d];
    float a0 = 0.f, a1 = 0.f;
    const int xbase = wid - n; // (t*B_+b)*N_
    for (int m = lane; m < N_; m += 64) {
        float dt = 0.f;
        #pragma unroll
        for (int d = 0; d < E_; ++d) dt += et[d] * nemb[m * E_ + d];
        float sg = sigm(dt);
        if (m == n) dmask[wid] = sg;
        float w = A[n * N_ + m] * sg;
        a0 += w * x[(xbase + m) * 2];
        a1 += w * x[(xbase + m) * 2 + 1];
    }
    a0 = wsum(a0);
    a1 = wsum(a1);
    if (lane == 0) { aggx[wid * 2] = a0; aggx[wid * 2 + 1] = a1; }
}

// ---------------- per-step: masked 64-ch aggregation aggS[b,n,:] = sum_m Am*Sin[b,m,:] ----------------
__global__ __launch_bounds__(256) void aggS_kernel(
    const float* __restrict__ A, const float* __restrict__ emb,
    const float* __restrict__ nemb, const float* __restrict__ Sin,
    float* __restrict__ aggS, int t) {
    __shared__ float emb_s[32][E_];
    __shared__ float ne_s[32][E_];
    __shared__ float w_s[32][33];
    __shared__ float s_s[32][64];
    const int n0 = blockIdx.x * 32;
    const int b = blockIdx.y;
    const int tid = threadIdx.x;
    for (int idx = tid; idx < 32 * E_; idx += 256) {
        int nl = idx / E_, d = idx % E_;
        int n = n0 + nl;
        emb_s[nl][d] = (n < N_) ? emb[((t * B_ + b) * N_ + n) * E_ + d] : 0.f;
    }
    const int ng = tid >> 4, ig = tid & 15;
    const int nl0 = ng * 2, i0 = ig * 4;
    float acc[2][4] = {};
    for (int m0 = 0; m0 < N_; m0 += 32) {
        __syncthreads();
        for (int idx = tid; idx < 32 * E_; idx += 256) {
            int ml = idx / E_, d = idx % E_;
            int m = m0 + ml;
            ne_s[ml][d] = (m < N_) ? nemb[m * E_ + d] : 0.f;
        }
        for (int idx = tid; idx < 32 * 64; idx += 256) {
            int ml = idx >> 6, i = idx & 63;
            int m = m0 + ml;
            s_s[ml][i] = (m < N_) ? Sin[(b * N_ + m) * 64 + i] : 0.f;
        }
        __syncthreads();
        for (int idx = tid; idx < 32 * 32; idx += 256) {
            int nl = idx >> 5, ml = idx & 31;
            int n = n0 + nl, m = m0 + ml;
            float w = 0.f;
            if (n < N_ && m < N_) {
                float dt = 0.f;
                #pragma unroll
                for (int e = 0; e < E_; ++e) dt += emb_s[nl][e] * ne_s[ml][e];
                w = A[n * N_ + m] * sigm(dt);
            }
            w_s[nl][ml] = w;
        }
        __syncthreads();
        #pragma unroll 8
        for (int ml = 0; ml < 32; ++ml) {
            float w0 = w_s[nl0][ml], w1 = w_s[nl0 + 1][ml];
            float4 sv = *(const float4*)&s_s[ml][i0];
            acc[0][0] += w0 * sv.x; acc[0][1] += w0 * sv.y;
            acc[0][2] += w0 * sv.z; acc[0][3] += w0 * sv.w;
            acc[1][0] += w1 * sv.x; acc[1][1] += w1 * sv.y;
            acc[1][2] += w1 * sv.z; acc[1][3] += w1 * sv.w;
        }
    }
    #pragma unroll
    for (int r = 0; r < 2; ++r) {
        int n = n0 + nl0 + r;
        if (n < N_) {
            float4 v = make_float4(acc[r][0], acc[r][1], acc[r][2], acc[r][3]);
            *(float4*)&aggS[(b * N_ + n) * 64 + i0] = v;
        }
    }
}

// ---------------- per-step: gate matmul -> zs, r ----------------
__global__ __launch_bounds__(256) void gate_mm_kernel(
    const float* __restrict__ gate_W, const float* __restrict__ gate_b,
    const float* __restrict__ x, const float* __restrict__ S,
    const float* __restrict__ dmask, const float* __restrict__ aggx,
    const float* __restrict__ aggS, float* __restrict__ zs,
    float* __restrict__ rbuf, int t) {
    __shared__ float W_s[132][64];
    __shared__ float xg_s[32][132];
    const int oh = blockIdx.x, bh = blockIdx.y, n = blockIdx.z;
    const int tid = threadIdx.x;
    for (int idx = tid; idx < 132 * 64; idx += 256) {
        int row = idx >> 6, op = idx & 63;
        int col = (op < 32) ? (oh * 32 + op) : (64 + oh * 32 + (op - 32));
        W_s[row][op] = gate_W[(n * 132 + row) * GO_ + col];
    }
    for (int idx = tid; idx < 32 * 132; idx += 256) {
        int bl = idx / 132, i = idx % 132;
        int b = bh * 32 + bl;
        int tb = (t * B_ + b) * N_ + n;
        float v;
        if (i < 66) {
            float xs = (i == 0) ? x[tb * 2] : (i == 1) ? x[tb * 2 + 1] : S[(b * N_ + n) * 64 + (i - 2)];
            v = dmask[tb] * xs;
        } else {
            int i2 = i - 66;
            v = (i2 < 2) ? aggx[tb * 2 + i2] : aggS[(b * N_ + n) * 64 + (i2 - 2)];
        }
        xg_s[bl][i] = v;
    }
    __syncthreads();
    const int bl = tid >> 3, og = tid & 7;
    float acc[8] = {};
    for (int i = 0; i < 132; ++i) {
        float xv = xg_s[bl][i];
        #pragma unroll
        for (int r = 0; r < 8; ++r) acc[r] += xv * W_s[i][og * 8 + r];
    }
    float v[8];
    #pragma unroll
    for (int r = 0; r < 8; ++r) {
        int op = og * 8 + r;
        int col = (op < 32) ? (oh * 32 + op) : (64 + oh * 32 + (op - 32));
        v[r] = sigm(acc[r] + gate_b[n * GO_ + col]);
    }
    __syncthreads();
    float* zr_s = &xg_s[0][0];
    #pragma unroll
    for (int r = 0; r < 8; ++r) zr_s[bl * 64 + og * 8 + r] = v[r];
    __syncthreads();
    for (int idx = tid; idx < 32 * 32; idx += 256) {
        int bl2 = idx >> 5, jl = idx & 31;
        int b = bh * 32 + bl2;
        int j = oh * 32 + jl;
        float z = zr_s[bl2 * 64 + jl];
        float rr = zr_s[bl2 * 64 + 32 + jl];
        int sidx = (b * N_ + n) * 64 + j;
        zs[sidx] = z * S[sidx];
        rbuf[sidx] = rr;
    }
}

// ---------------- per-step: update matmul + state update (in place) ----------------
__global__ __launch_bounds__(256) void upd_mm_kernel(
    const float* __restrict__ upd_W, const float* __restrict__ upd_b,
    const float* __restrict__ x, const float* __restrict__ zsrc,
    const float* __restrict__ dmask, const float* __restrict__ aggx,
    const float* __restrict__ aggS, const float* __restrict__ rbuf,
    float* __restrict__ S, int t) {
    __shared__ float W_s[132][64];
    __shared__ float xg_s[32][132];
    const int bh = blockIdx.x, n = blockIdx.y;
    const int tid = threadIdx.x;
    for (int idx = tid; idx < 132 * 64; idx += 256) {
        int row = idx >> 6, op = idx & 63;
        W_s[row][op] = upd_W[(n * 132 + row) * UO_ + op];
    }
    for (int idx = tid; idx < 32 * 132; idx += 256) {
        int bl = idx / 132, i = idx % 132;
        int b = bh * 32 + bl;
        int tb = (t * B_ + b) * N_ + n;
        float v;
        if (i < 66) {
            float xs = (i == 0) ? x[tb * 2] : (i == 1) ? x[tb * 2 + 1] : zsrc[(b * N_ + n) * 64 + (i - 2)];
            v = dmask[tb] * xs;
        } else {
            int i2 = i - 66;
            v = (i2 < 2) ? aggx[tb * 2 + i2] : aggS[(b * N_ + n) * 64 + (i2 - 2)];
        }
        xg_s[bl][i] = v;
    }
    __syncthreads();
    const int bl = tid >> 3, og = tid & 7;
    float acc[8] = {};
    for (int i = 0; i < 132; ++i) {
        float xv = xg_s[bl][i];
        #pragma unroll
        for (int r = 0; r < 8; ++r) acc[r] += xv * W_s[i][og * 8 + r];
    }
    const int b = bh * 32 + bl;
    #pragma unroll
    for (int r = 0; r < 8; ++r) {
        int op = og * 8 + r;
        float hc = ftanh(acc[r] + upd_b[n * UO_ + op]);
        int sidx = (b * N_ + n) * 64 + op;
        float rr = rbuf[sidx];
        float sv = S[sidx];
        S[sidx] = rr * sv + (1.f - rr) * hc;
    }
}

// ---------------- final: layernorm + end linear ----------------
__global__ __launch_bounds__(256) void final_kernel(
    const float* __restrict__ S, const float* __restrict__ gamma,
    const float* __restrict__ beta, const float* __restrict__ endW,
    const float* __restrict__ endb, float* __restrict__ out) {
    const int wid = blockIdx.x * 4 + (threadIdx.x >> 6);
    const int lane = threadIdx.x & 63;
    const int b = wid / N_, n = wid % N_;
    float s = S[wid * 64 + lane];
    float mu = wsum(s) * (1.f / 64.f);
    float d = s - mu;
    float var = wsum(d * d) * (1.f / 64.f);
    float xn = d / sqrtf(var + 1e-12f) * gamma[lane] + beta[lane];
    #pragma unroll
    for (int o = 0; o < 12; ++o) {
        float dot = wsum(xn * endW[o * 64 + lane]);
        if (lane == o) out[(b * 12 + o) * N_ + n] = dot + endb[o];
    }
}

extern "C" void kernel_launch(void* const* d_in, const int* in_sizes, int n_in,
                              void* d_out, int out_size, void* d_ws, size_t ws_size,
                              hipStream_t stream) {
    const float* hyper_source = (const float*)d_in[0];
    const float* source       = (const float*)d_in[1];
    const float* adj          = (const float*)d_in[2];
    const float* nemb         = (const float*)d_in[3];
    const float* mwpool       = (const float*)d_in[4];
    const float* hyper_W      = (const float*)d_in[5];
    const float* hyper_b      = (const float*)d_in[6];
    const float* mask_W1      = (const float*)d_in[7];
    const float* mask_W2      = (const float*)d_in[8];
    const float* gate_Wpool   = (const float*)d_in[9];
    const float* gate_bpool   = (const float*)d_in[10];
    const float* upd_Wpool    = (const float*)d_in[11];
    const float* upd_bpool    = (const float*)d_in[12];
    const float* ln_gamma     = (const float*)d_in[13];
    const float* ln_beta      = (const float*)d_in[14];
    const float* end_W        = (const float*)d_in[15];
    const float* end_b        = (const float*)d_in[16];
    float* out = (float*)d_out;

    float* ws = (float*)d_ws;
    size_t off = 0;
    auto alloc = [&](size_t nf) {
        float* p = ws + off;
        off += (nf + 255) & ~(size_t)255;
        return p;
    };
    float* A      = alloc((size_t)N_ * N_);
    float* wh     = alloc((size_t)N_ * H_);
    float* W12    = alloc((size_t)H_ * E_);
    float* gate_W = alloc((size_t)N_ * QG_);
    float* gate_b = alloc((size_t)N_ * GO_);
    float* upd_W  = alloc((size_t)N_ * QU_);
    float* upd_b  = alloc((size_t)N_ * UO_);
    float* x      = alloc((size_t)T_ * B_ * N_ * 2);
    float* emb    = alloc((size_t)T_ * B_ * N_ * E_);
    float* dmask  = alloc((size_t)T_ * B_ * N_);
    float* aggx   = alloc((size_t)T_ * B_ * N_ * 2);
    float* S      = alloc((size_t)B_ * N_ * H_);
    float* zs     = alloc((size_t)B_ * N_ * H_);
    float* rbuf   = alloc((size_t)B_ * N_ * H_);
    float* aggS   = alloc((size_t)B_ * N_ * H_);

    hipMemsetAsync(S, 0, (size_t)B_ * N_ * H_ * sizeof(float), stream);

    A_kernel<<<N_, 64, 0, stream>>>(adj, nemb, A);

    const int gen_total = N_ * QG_ + N_ * GO_ + N_ * QU_ + N_ * UO_ + N_ * H_ + H_ * E_;
    gen_kernel<<<(gen_total + 255) / 256, 256, 0, stream>>>(
        nemb, gate_Wpool, gate_bpool, upd_Wpool, upd_bpool, mwpool, mask_W1, mask_W2,
        gate_W, gate_b, upd_W, upd_b, wh, W12);

    const int nwaves = T_ * B_ * N_; // 235776, divisible by 4
    hyper_kernel<<<nwaves / 4, 256, 0, stream>>>(hyper_source, source, hyper_W, hyper_b, wh,
                                                 W12, x, emb);
    maskx_kernel<<<nwaves / 4, 256, 0, stream>>>(A, emb, nemb, x, dmask, aggx);

    for (int t = 0; t < T_; ++t) {
        aggS_kernel<<<dim3(10, B_), 256, 0, stream>>>(A, emb, nemb, S, aggS, t);
        gate_mm_kernel<<<dim3(2, 2, N_), 256, 0, stream>>>(gate_W, gate_b, x, S, dmask, aggx,
                                                           aggS, zs, rbuf, t);
        aggS_kernel<<<dim3(10, B_), 256, 0, stream>>>(A, emb, nemb, zs, aggS, t);
        upd_mm_kernel<<<dim3(2, N_), 256, 0, stream>>>(upd_W, upd_b, x, zs, dmask, aggx, aggS,
                                                       rbuf, S, t);
    }

    final_kernel<<<(B_ * N_) / 4, 256, 0, stream>>>(S, ln_gamma, ln_beta, end_W, end_b, out);
}